// Round 1
// baseline (413.505 us; speedup 1.0000x reference)
//
#include <hip/hip_runtime.h>

// Problem constants (fixed by the reference)
#define MM 8192
#define NN 4096
#define KK 4096

// GEMM tiling: 256x256 block tile, BK=128 int8 (4 K-steps of 32 per LDS tile)
#define BM 256
#define BN 256
#define BK 128
#define NT (KK / BK)        // 32 K-tiles
#define ABUF (BM * BK)      // 32 KB per A buffer
#define BBUF (BN * BK)      // 32 KB per B buffer

typedef int int32x4  __attribute__((ext_vector_type(4)));
typedef int int32x16 __attribute__((ext_vector_type(16)));

// ---------------------------------------------------------------------------
// Async global->LDS, 16B per lane. LDS destination is wave-uniform base +
// lane*16 (m104/m108); global source address is per-lane free (used for the
// bank-conflict swizzle).
// ---------------------------------------------------------------------------
__device__ __forceinline__ void async_load16(const void* g, void* l) {
  __builtin_amdgcn_global_load_lds(
      (__attribute__((address_space(1))) void*)(void*)g,
      (__attribute__((address_space(3))) void*)l,
      16, 0, 0);
}

// ---------------------------------------------------------------------------
// Pack kernel: int32 (int8-range) -> int8, subtracting zero points.
// 16 elements/thread: 4x dwordx4 loads (64B/lane) -> pack -> ONE dwordx4
// store (wave writes 1KB contiguous).
//   A: M*K/16 = 2,097,152 threads -> 8192 blocks of 256 (exact)
//   W: N*K/16 = 1,048,576 threads -> 4096 blocks of 256 (exact)
// A/W boundary is block-aligned (no intra-block divergence). Each thread's
// 16 elements sit inside one weight row (K=4096 divisible by 16).
// ---------------------------------------------------------------------------
__global__ __launch_bounds__(256) void pack_kernel(
    const int* __restrict__ a, const int* __restrict__ w,
    char* __restrict__ a8, char* __restrict__ w8,
    const int* __restrict__ izp, const int* __restrict__ wzp) {
  const long tid = (long)blockIdx.x * 256 + threadIdx.x;
  const long A_T = (long)MM * KK / 16;

  const int4* src;
  int4* dst;
  int z;
  if (tid < A_T) {
    src = (const int4*)a + tid * 4;
    dst = (int4*)a8 + tid;
    z = izp[0];
  } else {
    const long t = tid - A_T;
    src = (const int4*)w + t * 4;
    dst = (int4*)w8 + t;
    z = wzp[t >> 8];  // K/16 = 256 threads per weight row
  }

  int4 v0 = src[0], v1 = src[1], v2 = src[2], v3 = src[3];
  union { char c[16]; int4 q; } u;
  u.c[0]  = (char)(v0.x - z); u.c[1]  = (char)(v0.y - z);
  u.c[2]  = (char)(v0.z - z); u.c[3]  = (char)(v0.w - z);
  u.c[4]  = (char)(v1.x - z); u.c[5]  = (char)(v1.y - z);
  u.c[6]  = (char)(v1.z - z); u.c[7]  = (char)(v1.w - z);
  u.c[8]  = (char)(v2.x - z); u.c[9]  = (char)(v2.y - z);
  u.c[10] = (char)(v2.z - z); u.c[11] = (char)(v2.w - z);
  u.c[12] = (char)(v3.x - z); u.c[13] = (char)(v3.y - z);
  u.c[14] = (char)(v3.z - z); u.c[15] = (char)(v3.w - z);
  *dst = u.q;
}

// ---------------------------------------------------------------------------
// int8 GEMM, 8-phase-style counted-vmcnt schedule (T3+T4+T5):
//   C[m][n] = sum_k A8[m][k] * W8[n][k];  out = is*ws[n]*C + bias[n]
//
// 256x256 tile, BK=128, 512 threads = 8 waves (2m x 4n), wave tile 128x64 =
// 4x2 grid of v_mfma_i32_32x32x32_i8 (acc 128 VGPRs). LDS double buffer
// 2x(32+32) KB = 128 KB -> 1 block/CU, 2 waves/SIMD.
//
// Per K-tile t: 4 phases (one K-step of 32 each):
//   phase = { 6x ds_read_b128 frags ; issue 2 global_load_lds (prefetch) ;
//             s_barrier ; setprio(1) ; 8x MFMA ; setprio(0) ; s_barrier }
// Load pairs: pair0=A rows 0..127, pair1=A rows 128..255, pair2=B rows
// 0..127, pair3=B rows 128..255. Tile tau's pairs issue at (tau-2).p3,
// (tau-1).p0, (tau-1).p1, (tau-1).p2 -> all landed one full phase before
// first use. K-tile boundary waits s_waitcnt vmcnt(2) (only the
// next-next-tile pair0 stays in flight) + raw s_barrier. NO __syncthreads
// anywhere in the loop => no vmcnt(0) drain.
//
// Swizzle (unchanged scheme, proven 0-conflict): 128B row = 8 subs of 16B;
// physical sub p of row r holds logical sub p^(r&7), applied by permuting
// the per-lane GLOBAL source address of global_load_lds. 32x32x32 A-frag:
// lane holds m=lane&31, k=(lane>>5)*16+j  => logical sub (2s + lane>>5),
// physical sub (2s + (lane>>5)) ^ (lane&7): 8 accesses/bank per wave64
// ds_read_b128 = the 8-cycle minimum.
// ---------------------------------------------------------------------------
__global__ __launch_bounds__(512, 2) void qgemm_kernel(
    const char* __restrict__ A8, const char* __restrict__ W8,
    float* __restrict__ out,
    const float* __restrict__ bias,
    const float* __restrict__ is_ptr,
    const float* __restrict__ wscale) {
  __shared__ __attribute__((aligned(16))) char As[2 * ABUF];  // 64 KB
  __shared__ __attribute__((aligned(16))) char Bs[2 * BBUF];  // 64 KB

  // ---- block swizzle: XCD-bijective (512 blocks, 512%8==0, cpx=64) ------
  // XCD x owns pids [64x,64x+64) -> bm in [4x,4x+4): 4 A-panels (4MB) stay
  // L2-resident per XCD, B streams from LLC.
  int pid = blockIdx.x;
  pid = (pid & 7) * 64 + (pid >> 3);
  const int bm = pid >> 4;  // 0..31
  const int bn = pid & 15;  // 0..15

  const int tid  = threadIdx.x;
  const int wid  = tid >> 6;
  const int lane = tid & 63;
  const int wm = (wid >> 2) * 128;  // 0 / 128
  const int wn = (wid & 3) * 64;    // 0 / 64 / 128 / 192

  // ---- staging addresses ------------------------------------------------
  // Tile = 256 rows x 128B = 32 chunks of 1KB (8 rows). Wave w stages
  // chunks {w, w+8, w+16, w+24} of A and of B (load index i = chunk/8).
  // Lane l -> row_in_chunk = l>>3, physical sub = l&7,
  //           logical (global) sub = (l&7) ^ ((l>>3)&7).
  const int srow = lane >> 3;
  const int ssub = (lane & 7) ^ (srow & 7);
  const char* a_src[4];
  const char* b_src[4];
  int a_off[4];
#pragma unroll
  for (int i = 0; i < 4; ++i) {
    const int c = wid + i * 8;  // chunk 0..31
    a_src[i] = A8 + (long)(bm * BM + c * 8 + srow) * KK + ssub * 16;
    b_src[i] = W8 + (long)(bn * BN + c * 8 + srow) * KK + ssub * 16;
    a_off[i] = c * 1024;
  }

#define STAGE_A(I, T) \
  async_load16(a_src[I] + (T) * BK, As + ((T) & 1) * ABUF + a_off[I])
#define STAGE_B(I, T) \
  async_load16(b_src[I] + (T) * BK, Bs + ((T) & 1) * BBUF + a_off[I])

  // ---- fragment read addressing -----------------------------------------
  const int r31 = lane & 31;
  const int hi  = lane >> 5;
  const int l7  = lane & 7;
  const char* a_rd = As + (wm + r31) * BK;
  const char* b_rd = Bs + (wn + r31) * BK;
  // physical sub byte offset per K-step s:
  const int ps0 = (((0 + hi) ^ l7) * 16);
  const int ps1 = (((2 + hi) ^ l7) * 16);
  const int ps2 = (((4 + hi) ^ l7) * 16);
  const int ps3 = (((6 + hi) ^ l7) * 16);

  int32x16 acc[4][2];
#pragma unroll
  for (int mi = 0; mi < 4; ++mi)
#pragma unroll
    for (int ni = 0; ni < 2; ++ni) acc[mi][ni] = (int32x16)0;

  // ---- prologue: tile 0 fully + pair0 of tile 1 -------------------------
#pragma unroll
  for (int i = 0; i < 4; ++i) STAGE_A(i, 0);
#pragma unroll
  for (int i = 0; i < 4; ++i) STAGE_B(i, 0);
  STAGE_A(0, 1);
  STAGE_A(1, 1);
  asm volatile("s_waitcnt vmcnt(2)" ::: "memory");
  __builtin_amdgcn_s_barrier();

#define PHASE(PS, CUR, STAGE_STMT)                                          \
  {                                                                         \
    const char* ar_ = a_rd + (CUR) * ABUF;                                  \
    const char* br_ = b_rd + (CUR) * BBUF;                                  \
    int32x4 af0 = *(const int32x4*)(ar_ + 0 * 32 * BK + (PS));              \
    int32x4 af1 = *(const int32x4*)(ar_ + 1 * 32 * BK + (PS));              \
    int32x4 af2 = *(const int32x4*)(ar_ + 2 * 32 * BK + (PS));              \
    int32x4 af3 = *(const int32x4*)(ar_ + 3 * 32 * BK + (PS));              \
    int32x4 bf0 = *(const int32x4*)(br_ + 0 * 32 * BK + (PS));              \
    int32x4 bf1 = *(const int32x4*)(br_ + 1 * 32 * BK + (PS));              \
    STAGE_STMT;                                                             \
    __builtin_amdgcn_s_barrier();                                           \
    __builtin_amdgcn_s_setprio(1);                                          \
    acc[0][0] = __builtin_amdgcn_mfma_i32_32x32x32_i8(af0, bf0, acc[0][0], 0, 0, 0); \
    acc[0][1] = __builtin_amdgcn_mfma_i32_32x32x32_i8(af0, bf1, acc[0][1], 0, 0, 0); \
    acc[1][0] = __builtin_amdgcn_mfma_i32_32x32x32_i8(af1, bf0, acc[1][0], 0, 0, 0); \
    acc[1][1] = __builtin_amdgcn_mfma_i32_32x32x32_i8(af1, bf1, acc[1][1], 0, 0, 0); \
    acc[2][0] = __builtin_amdgcn_mfma_i32_32x32x32_i8(af2, bf0, acc[2][0], 0, 0, 0); \
    acc[2][1] = __builtin_amdgcn_mfma_i32_32x32x32_i8(af2, bf1, acc[2][1], 0, 0, 0); \
    acc[3][0] = __builtin_amdgcn_mfma_i32_32x32x32_i8(af3, bf0, acc[3][0], 0, 0, 0); \
    acc[3][1] = __builtin_amdgcn_mfma_i32_32x32x32_i8(af3, bf1, acc[3][1], 0, 0, 0); \
    __builtin_amdgcn_s_setprio(0);                                          \
  }

  // ---- main loop: 4 phases per K-tile, counted-vmcnt boundary -----------
#pragma unroll 2
  for (int t = 0; t < NT; ++t) {
    const int cur = t & 1;
    // phase 0: K-step 0, prefetch pair1(t+1) = A rows 128..255
    PHASE(ps0, cur, if (t + 1 < NT) { STAGE_A(2, t + 1); STAGE_A(3, t + 1); })
    __builtin_amdgcn_s_barrier();
    // phase 1: K-step 1, prefetch pair2(t+1) = B rows 0..127
    PHASE(ps1, cur, if (t + 1 < NT) { STAGE_B(0, t + 1); STAGE_B(1, t + 1); })
    __builtin_amdgcn_s_barrier();
    // phase 2: K-step 2, prefetch pair3(t+1) = B rows 128..255
    PHASE(ps2, cur, if (t + 1 < NT) { STAGE_B(2, t + 1); STAGE_B(3, t + 1); })
    __builtin_amdgcn_s_barrier();
    // phase 3: K-step 3, prefetch pair0(t+2) = A rows 0..127 (overwrites the
    // buffer whose last ds_reads were just issued above in program order;
    // ~500cy load latency >> wave skew — the template-verified pattern)
    PHASE(ps3, cur, if (t + 2 < NT) { STAGE_A(0, t + 2); STAGE_A(1, t + 2); })
    // boundary: everything for t+1 landed; only t+2's pair0 (2 loads) in flight
    asm volatile("s_waitcnt vmcnt(2)" ::: "memory");
    __builtin_amdgcn_s_barrier();
  }

  // ---- epilogue: out = is * ws[n] * acc + bias[n] -----------------------
  // C/D layout (32x32): col = lane&31, row = (r&3) + 8*(r>>2) + 4*(lane>>5)
  const float is0 = is_ptr[0];
  const int row_base = bm * BM + wm + 4 * hi;
  const int col_base = bn * BN + wn + r31;
#pragma unroll
  for (int ni = 0; ni < 2; ++ni) {
    const int col = col_base + ni * 32;
    const float s = is0 * wscale[col];
    const float b = bias[col];
#pragma unroll
    for (int mi = 0; mi < 4; ++mi) {
      const long rb = (long)(row_base + mi * 32) * NN + col;
#pragma unroll
      for (int r = 0; r < 16; ++r) {
        const int roff = (r & 3) + 8 * (r >> 2);
        out[rb + (long)roff * NN] = (float)acc[mi][ni][r] * s + b;
      }
    }
  }
#undef PHASE
#undef STAGE_A
#undef STAGE_B
}

// ---------------------------------------------------------------------------
extern "C" void kernel_launch(void* const* d_in, const int* in_sizes, int n_in,
                              void* d_out, int out_size, void* d_ws, size_t ws_size,
                              hipStream_t stream) {
  const int*   inp    = (const int*)d_in[0];    // [M,K] int32 (int8-range)
  const int*   weight = (const int*)d_in[1];    // [N,K] int32 (int8-range)
  const float* bias   = (const float*)d_in[2];  // [N]
  const float* iscale = (const float*)d_in[3];  // [1]
  const int*   izp    = (const int*)d_in[4];    // [1]
  const float* wscale = (const float*)d_in[5];  // [N]
  const int*   wzp    = (const int*)d_in[6];    // [N]
  float* out = (float*)d_out;

  char* a8 = (char*)d_ws;                        // M*K  = 33.5 MB
  char* w8 = a8 + (size_t)MM * KK;               // N*K  = 16.8 MB (total 50.3 MB)

  // pack: (M*K + N*K)/16 threads -> 12288 blocks of 256 (exact)
  pack_kernel<<<12288, 256, 0, stream>>>(inp, weight, a8, w8, izp, wzp);

  // GEMM: 32 * 16 = 512 blocks of 512 threads (8 waves), 1 block/CU
  qgemm_kernel<<<512, 512, 0, stream>>>(a8, w8, out, bias, iscale, wscale);
}

// Round 2
// 404.270 us; speedup vs baseline: 1.0228x; 1.0228x over previous
//
#include <hip/hip_runtime.h>

// Problem constants (fixed by the reference)
#define MM 8192
#define NN 4096
#define KK 4096

// GEMM tiling: 256x256 block tile, BK=64 int8 (2 K-steps of 32 per LDS tile),
// 4-deep LDS ring buffer => never-drain counted-vmcnt pipeline.
#define BM 256
#define BN 256
#define BK 64
#define NT (KK / BK)          // 64 K-tiles
#define SLOT_BYTES 32768      // 16KB A + 16KB B per ring slot
#define B_OFF 16384           // B region offset within a slot

typedef int int32x4  __attribute__((ext_vector_type(4)));
typedef int int32x16 __attribute__((ext_vector_type(16)));

// ---------------------------------------------------------------------------
// Async global->LDS, 16B per lane. LDS destination is wave-uniform base +
// lane*16 (m104/m108); global source address is per-lane free (used for the
// bank-conflict swizzle).
// ---------------------------------------------------------------------------
__device__ __forceinline__ void async_load16(const void* g, void* l) {
  __builtin_amdgcn_global_load_lds(
      (__attribute__((address_space(1))) void*)(void*)g,
      (__attribute__((address_space(3))) void*)l,
      16, 0, 0);
}

// ---------------------------------------------------------------------------
// Pack kernel: int32 (int8-range) -> int8, subtracting zero points.
// 16 elements/thread: 4x dwordx4 loads (64B/lane) -> pack -> ONE dwordx4
// store (wave writes 1KB contiguous).
// ---------------------------------------------------------------------------
__global__ __launch_bounds__(256) void pack_kernel(
    const int* __restrict__ a, const int* __restrict__ w,
    char* __restrict__ a8, char* __restrict__ w8,
    const int* __restrict__ izp, const int* __restrict__ wzp) {
  const long tid = (long)blockIdx.x * 256 + threadIdx.x;
  const long A_T = (long)MM * KK / 16;

  const int4* src;
  int4* dst;
  int z;
  if (tid < A_T) {
    src = (const int4*)a + tid * 4;
    dst = (int4*)a8 + tid;
    z = izp[0];
  } else {
    const long t = tid - A_T;
    src = (const int4*)w + t * 4;
    dst = (int4*)w8 + t;
    z = wzp[t >> 8];  // K/16 = 256 threads per weight row
  }

  int4 v0 = src[0], v1 = src[1], v2 = src[2], v3 = src[3];
  union { char c[16]; int4 q; } u;
  u.c[0]  = (char)(v0.x - z); u.c[1]  = (char)(v0.y - z);
  u.c[2]  = (char)(v0.z - z); u.c[3]  = (char)(v0.w - z);
  u.c[4]  = (char)(v1.x - z); u.c[5]  = (char)(v1.y - z);
  u.c[6]  = (char)(v1.z - z); u.c[7]  = (char)(v1.w - z);
  u.c[8]  = (char)(v2.x - z); u.c[9]  = (char)(v2.y - z);
  u.c[10] = (char)(v2.z - z); u.c[11] = (char)(v2.w - z);
  u.c[12] = (char)(v3.x - z); u.c[13] = (char)(v3.y - z);
  u.c[14] = (char)(v3.z - z); u.c[15] = (char)(v3.w - z);
  *dst = u.q;
}

// ---------------------------------------------------------------------------
// int8 GEMM, 4-deep-ring counted-vmcnt schedule:
//   C[m][n] = sum_k A8[m][k] * W8[n][k];  out = is*ws[n]*C + bias[n]
//
// 256x256 tile, BK=64, 512 threads = 8 waves (2m x 4n), wave tile 128x64 =
// 4x2 grid of v_mfma_i32_32x32x32_i8. LDS = 4 ring slots x 32KB = 128 KB.
//
// Pipeline (per wave): phase 0 of tile t issues the A-pair of tile t+3;
// phase 1 issues the B-pair of t+3. Steady state: 8 loads in flight
// (A/B of t+1 and t+2 have landed; t+3 streaming). Tile entry:
//   s_waitcnt vmcnt(8)  -> own A(t),B(t) landed, 8 newer stay in flight
//   s_barrier           -> all waves' slot-t data visible; bounds skew <1 tile
// ONE barrier per tile. Safety: writes target slot (t+3)&3; the only reader
// of that physical slot was tile t-1, whose ds_reads completed (lgkmcnt
// before its MFMAs) before any wave passed this tile's barrier. Within-wave
// RAW likewise covered by compiler lgkmcnt. Never a vmcnt(0) drain.
//
// Swizzle for 64B LDS rows (4 subs of 16B): physical sub p of row r holds
// logical p ^ ((r>>1)&3), applied by permuting the per-lane GLOBAL source of
// global_load_lds (LDS dest stays linear). Fragment read (32x32x32, K-step s):
// lane(m=lane&31, hi=lane>>5) reads logical sub 2s+hi of row m -> physical
// (2s+hi) ^ ((m>>1)&3). Bank 4-group = 4*(r&1) + phys: aggregate 8 lanes per
// 4-bank group (the wave64 b128 minimum) AND every 8 consecutive lanes hit 8
// distinct groups. Staging writes are linear 1KB bursts (conflict-free).
// ---------------------------------------------------------------------------
__global__ __launch_bounds__(512, 2) void qgemm_kernel(
    const char* __restrict__ A8, const char* __restrict__ W8,
    float* __restrict__ out,
    const float* __restrict__ bias,
    const float* __restrict__ is_ptr,
    const float* __restrict__ wscale) {
  __shared__ __attribute__((aligned(16))) char lds[4 * SLOT_BYTES];  // 128 KB

  // ---- block swizzle: XCD-bijective (512 blocks, 512%8==0, cpx=64) ------
  int pid = blockIdx.x;
  pid = (pid & 7) * 64 + (pid >> 3);
  const int bm = pid >> 4;  // 0..31
  const int bn = pid & 15;  // 0..15

  const int tid  = threadIdx.x;
  const int wid  = tid >> 6;
  const int lane = tid & 63;
  const int wm = (wid >> 2) * 128;  // 0 / 128
  const int wn = (wid & 3) * 64;    // 0 / 64 / 128 / 192

  // ---- staging addresses ------------------------------------------------
  // Tile half (A or B) = 256 rows x 64B = 16 chunks of 1KB (16 rows each).
  // Wave w stages chunks {w, w+8} of A and of B.
  // Lane l -> row_in_chunk = l>>2, physical sub = l&3,
  //           logical (global) sub = (l&3) ^ ((l>>3)&3)   [row>>1 == l>>3]
  const int srow = lane >> 2;
  const int ssub = (lane & 3) ^ ((lane >> 3) & 3);
  const char* a_src[2];
  const char* b_src[2];
  int c_off[2];
#pragma unroll
  for (int i = 0; i < 2; ++i) {
    const int c = wid + i * 8;  // chunk 0..15
    a_src[i] = A8 + (long)(bm * BM + c * 16 + srow) * KK + ssub * 16;
    b_src[i] = W8 + (long)(bn * BN + c * 16 + srow) * KK + ssub * 16;
    c_off[i] = c * 1024;
  }

#define STAGE_A(I, T) \
  async_load16(a_src[I] + (T) * BK, lds + ((T) & 3) * SLOT_BYTES + c_off[I])
#define STAGE_B(I, T) \
  async_load16(b_src[I] + (T) * BK, lds + ((T) & 3) * SLOT_BYTES + B_OFF + c_off[I])

  // ---- fragment read addressing -----------------------------------------
  const int r31 = lane & 31;
  const int hi  = lane >> 5;
  const int rx  = (r31 >> 1) & 3;
  const int ps0 = ((0 + hi) ^ rx) * 16;  // K-step 0
  const int ps1 = ((2 + hi) ^ rx) * 16;  // K-step 1
  const int a_row = (wm + r31) * BK;     // byte offset of row in A region
  const int b_row = (wn + r31) * BK;     // byte offset of row in B region

  int32x16 acc[4][2];
#pragma unroll
  for (int mi = 0; mi < 4; ++mi)
#pragma unroll
    for (int ni = 0; ni < 2; ++ni) acc[mi][ni] = (int32x16)0;

  // ---- prologue: tiles 0,1,2 fully staged (12 loads, oldest = tile 0) ---
#pragma unroll
  for (int t0 = 0; t0 < 3; ++t0) {
    STAGE_A(0, t0); STAGE_A(1, t0);
    STAGE_B(0, t0); STAGE_B(1, t0);
  }

#define PHASE(PS, SB, STAGE_STMT)                                            \
  {                                                                          \
    const char* ar_ = lds + (SB) + a_row;                                    \
    const char* br_ = lds + (SB) + B_OFF + b_row;                            \
    int32x4 af0 = *(const int32x4*)(ar_ + 0 * 32 * BK + (PS));               \
    int32x4 af1 = *(const int32x4*)(ar_ + 1 * 32 * BK + (PS));               \
    int32x4 af2 = *(const int32x4*)(ar_ + 2 * 32 * BK + (PS));               \
    int32x4 af3 = *(const int32x4*)(ar_ + 3 * 32 * BK + (PS));               \
    int32x4 bf0 = *(const int32x4*)(br_ + 0 * 32 * BK + (PS));               \
    int32x4 bf1 = *(const int32x4*)(br_ + 1 * 32 * BK + (PS));               \
    STAGE_STMT;                                                              \
    __builtin_amdgcn_s_setprio(1);                                           \
    acc[0][0] = __builtin_amdgcn_mfma_i32_32x32x32_i8(af0, bf0, acc[0][0], 0, 0, 0); \
    acc[0][1] = __builtin_amdgcn_mfma_i32_32x32x32_i8(af0, bf1, acc[0][1], 0, 0, 0); \
    acc[1][0] = __builtin_amdgcn_mfma_i32_32x32x32_i8(af1, bf0, acc[1][0], 0, 0, 0); \
    acc[1][1] = __builtin_amdgcn_mfma_i32_32x32x32_i8(af1, bf1, acc[1][1], 0, 0, 0); \
    acc[2][0] = __builtin_amdgcn_mfma_i32_32x32x32_i8(af2, bf0, acc[2][0], 0, 0, 0); \
    acc[2][1] = __builtin_amdgcn_mfma_i32_32x32x32_i8(af2, bf1, acc[2][1], 0, 0, 0); \
    acc[3][0] = __builtin_amdgcn_mfma_i32_32x32x32_i8(af3, bf0, acc[3][0], 0, 0, 0); \
    acc[3][1] = __builtin_amdgcn_mfma_i32_32x32x32_i8(af3, bf1, acc[3][1], 0, 0, 0); \
    __builtin_amdgcn_s_setprio(0);                                           \
  }

  // ---- main loop: 2 phases per K-tile, ONE barrier per tile -------------
#pragma unroll 4
  for (int t = 0; t < NT; ++t) {
    const int sb = (t & 3) * SLOT_BYTES;
    // own A(t),B(t) landed; up to 8 newer loads stay in flight
    asm volatile("s_waitcnt vmcnt(8)" ::: "memory");
    __builtin_amdgcn_s_barrier();
    // phase 0: K-step 0; prefetch A-pair of tile t+3
    PHASE(ps0, sb, if (t < NT - 3) { STAGE_A(0, t + 3); STAGE_A(1, t + 3); })
    // phase 1: K-step 1; prefetch B-pair of tile t+3
    PHASE(ps1, sb, if (t < NT - 3) { STAGE_B(0, t + 3); STAGE_B(1, t + 3); })
  }

  // ---- epilogue: out = is * ws[n] * acc + bias[n] -----------------------
  // C/D layout (32x32): col = lane&31, row = (r&3) + 8*(r>>2) + 4*(lane>>5)
  const float is0 = is_ptr[0];
  const int row_base = bm * BM + wm + 4 * hi;
  const int col_base = bn * BN + wn + r31;
#pragma unroll
  for (int ni = 0; ni < 2; ++ni) {
    const int col = col_base + ni * 32;
    const float s = is0 * wscale[col];
    const float b = bias[col];
#pragma unroll
    for (int mi = 0; mi < 4; ++mi) {
      const long rb = (long)(row_base + mi * 32) * NN + col;
#pragma unroll
      for (int r = 0; r < 16; ++r) {
        const int roff = (r & 3) + 8 * (r >> 2);
        out[rb + (long)roff * NN] = (float)acc[mi][ni][r] * s + b;
      }
    }
  }
#undef PHASE
#undef STAGE_A
#undef STAGE_B
}

// ---------------------------------------------------------------------------
extern "C" void kernel_launch(void* const* d_in, const int* in_sizes, int n_in,
                              void* d_out, int out_size, void* d_ws, size_t ws_size,
                              hipStream_t stream) {
  const int*   inp    = (const int*)d_in[0];    // [M,K] int32 (int8-range)
  const int*   weight = (const int*)d_in[1];    // [N,K] int32 (int8-range)
  const float* bias   = (const float*)d_in[2];  // [N]
  const float* iscale = (const float*)d_in[3];  // [1]
  const int*   izp    = (const int*)d_in[4];    // [1]
  const float* wscale = (const float*)d_in[5];  // [N]
  const int*   wzp    = (const int*)d_in[6];    // [N]
  float* out = (float*)d_out;

  char* a8 = (char*)d_ws;                        // M*K  = 33.5 MB
  char* w8 = a8 + (size_t)MM * KK;               // N*K  = 16.8 MB (total 50.3 MB)

  // pack: (M*K + N*K)/16 threads -> 12288 blocks of 256 (exact)
  pack_kernel<<<12288, 256, 0, stream>>>(inp, weight, a8, w8, izp, wzp);

  // GEMM: 32 * 16 = 512 blocks of 512 threads (8 waves), 1 block/CU
  qgemm_kernel<<<512, 512, 0, stream>>>(a8, w8, out, bias, iscale, wscale);
}